// Round 3
// baseline (735.490 us; speedup 1.0000x reference)
//
#include <hip/hip_runtime.h>
#include <cstdint>

// out[b] = x[b] @ C[b],  C[b] = sum_h Wq[h] M[b,h] Wo[h],  M = Wk^T (x^T x) Wv
// R13: SINGLE persistent kernel.  R10..R12 showed +10.5us per launch
// (124.6/135.5/145.8 us at 4/5/6 launches) -- launch overhead dominates,
// kernel work is ~30us.  All 6 phases fused with hand-rolled device-wide
// barriers (monotonic counters, device-scope atomics, memset-zeroed).
// 512 blocks x 256 thr, 32KB dynamic LDS, launch_bounds(256,2) ->
// guaranteed 2 blocks/CU co-residency (512 resident) -> no deadlock.
// Phases: prep | xtx (G partials, split-K=8) | G-reduce->bf16 | gvm
// (T2=Wk^T G, M-partials bf16) | tail (sum M-partials, CT) | out.

#define BDIM 2
#define LDIM 4096
#define DIN 512
#define HDIM 8
#define DK 64
#define DV 64
#define DOUT 512
#define NCHUNK 8
#define NBLK 512
#define SMEM_BYTES 32768

using bf16_t = __bf16;
typedef __bf16 bf16x8 __attribute__((ext_vector_type(8)));
typedef float floatx4 __attribute__((ext_vector_type(4)));

constexpr size_t OFF_XB  = 4096;
constexpr size_t OFF_XT  = OFF_XB  + (size_t)BDIM * LDIM * DIN * 2;
constexpr size_t OFF_WQC = OFF_XT  + (size_t)BDIM * LDIM * DIN * 2;
constexpr size_t OFF_WKT = OFF_WQC + (size_t)DIN * HDIM * DK * 2;
constexpr size_t OFF_WVT = OFF_WKT + (size_t)HDIM * DK * DIN * 2;
constexpr size_t OFF_WOT = OFF_WVT + (size_t)HDIM * DV * DIN * 2;
constexpr size_t OFF_CT  = OFF_WOT + (size_t)HDIM * DOUT * DV * 2;
constexpr size_t OFF_GB  = OFF_CT  + (size_t)BDIM * DIN * DOUT * 2;
constexpr size_t OFF_MP  = OFF_GB  + (size_t)BDIM * DIN * DIN * 2;
constexpr size_t OFF_GP  = OFF_MP  + (size_t)NCHUNK * BDIM * HDIM * DK * DV * 2;

__device__ __forceinline__ unsigned short f2bf(float f) {
    unsigned int u = __builtin_bit_cast(unsigned int, f);
    u += 0x7FFFu + ((u >> 16) & 1u);
    return (unsigned short)(u >> 16);
}

__device__ __forceinline__ float bf2f(unsigned short u) {
    unsigned int v = ((unsigned int)u) << 16;
    return __builtin_bit_cast(float, v);
}

__device__ __forceinline__ void gld_lds16(const void* g, void* l) {
    __builtin_amdgcn_global_load_lds(
        (const __attribute__((address_space(1))) void*)g,
        (__attribute__((address_space(3))) void*)l, 16, 0, 0);
}

// Device-wide barrier: monotonic counter per call site, zeroed by host memset.
__device__ __forceinline__ void gbar(unsigned* bar, int idx) {
    __syncthreads();
    if (threadIdx.x == 0) {
        __threadfence();  // release my block's global writes (device scope)
        __hip_atomic_fetch_add(bar + idx, 1u, __ATOMIC_ACQ_REL,
                               __HIP_MEMORY_SCOPE_AGENT);
        while (__hip_atomic_load(bar + idx, __ATOMIC_ACQUIRE,
                                 __HIP_MEMORY_SCOPE_AGENT) < (unsigned)NBLK)
            __builtin_amdgcn_s_sleep(2);
    }
    __syncthreads();
    __threadfence();  // acquire: invalidate stale caches before next phase reads
}

// ---------------- TN MFMA GEMM tile, fp32 store ----------------
// C[m][n] = sum_k A[m][k] * B[n][k]
template <int BM, int BN, int BK>
__device__ __forceinline__ void gemm_tile(char* smem, const bf16_t* A,
                                          const bf16_t* B, float* Cp, int K,
                                          int lda, int ldb, int ldc, int tm,
                                          int tn) {
    constexpr int WM = BM / 2, WN = BN / 2;
    constexpr int FM = WM / 16, FN = WN / 16;
    constexpr int CPR = BK / 8;
    bf16_t* As = (bf16_t*)smem;
    bf16_t* Bs = As + BM * BK;
    const int tid = threadIdx.x;
    const int lane = tid & 63;
    const int wr = (tid >> 7) & 1;
    const int wc = (tid >> 6) & 1;

    A += (size_t)tm * lda;
    B += (size_t)tn * ldb;

    floatx4 acc[FM][FN] = {};

    for (int k0 = 0; k0 < K; k0 += BK) {
#pragma unroll
        for (int i = 0; i < (BM * CPR) / 256; ++i) {
            int c = i * 256 + tid;
            int m = c / CPR, kc = c % CPR;
            gld_lds16(A + (size_t)m * lda + k0 + kc * 8, As + c * 8);
        }
#pragma unroll
        for (int i = 0; i < (BN * CPR) / 256; ++i) {
            int c = i * 256 + tid;
            int m = c / CPR, kc = c % CPR;
            gld_lds16(B + (size_t)m * ldb + k0 + kc * 8, Bs + c * 8);
        }
        __syncthreads();

#pragma unroll
        for (int kk = 0; kk < BK; kk += 32) {
            bf16x8 aF[FM], bF[FN];
#pragma unroll
            for (int fm = 0; fm < FM; ++fm)
                aF[fm] = *(const bf16x8*)(As + (wr * WM + fm * 16 + (lane & 15)) * BK +
                                          kk + (lane >> 4) * 8);
#pragma unroll
            for (int fn = 0; fn < FN; ++fn)
                bF[fn] = *(const bf16x8*)(Bs + (wc * WN + fn * 16 + (lane & 15)) * BK +
                                          kk + (lane >> 4) * 8);
#pragma unroll
            for (int fm = 0; fm < FM; ++fm)
#pragma unroll
                for (int fn = 0; fn < FN; ++fn)
                    acc[fm][fn] = __builtin_amdgcn_mfma_f32_16x16x32_bf16(
                        aF[fm], bF[fn], acc[fm][fn], 0, 0, 0);
        }
        __syncthreads();
    }

    const int cr4 = (lane >> 4) * 4;
    const int cn = lane & 15;
#pragma unroll
    for (int fm = 0; fm < FM; ++fm)
#pragma unroll
        for (int fn = 0; fn < FN; ++fn)
#pragma unroll
            for (int r = 0; r < 4; ++r) {
                int m = tm + wr * WM + fm * 16 + cr4 + r;
                int n = tn + wc * WN + fn * 16 + cn;
                Cp[(size_t)m * ldc + n] = acc[fm][fn][r];
            }
}

__global__ __launch_bounds__(256, 2) void k_all(
    const float* __restrict__ x, const float* __restrict__ Wq,
    const float* __restrict__ Wk, const float* __restrict__ Wv,
    const float* __restrict__ Wo, char* __restrict__ ws,
    float* __restrict__ out) {
    extern __shared__ __align__(16) char smem[];
    unsigned* bar = (unsigned*)ws;
    unsigned short* xb  = (unsigned short*)(ws + OFF_XB);
    unsigned short* xT  = (unsigned short*)(ws + OFF_XT);
    unsigned short* WqC = (unsigned short*)(ws + OFF_WQC);
    unsigned short* WkT = (unsigned short*)(ws + OFF_WKT);
    unsigned short* WvT = (unsigned short*)(ws + OFF_WVT);
    unsigned short* WoT = (unsigned short*)(ws + OFF_WOT);
    unsigned short* CT  = (unsigned short*)(ws + OFF_CT);
    unsigned short* Gb  = (unsigned short*)(ws + OFF_GB);
    unsigned short* Mp  = (unsigned short*)(ws + OFF_MP);
    float* Gp = (float*)(ws + OFF_GP);

    const int bid = blockIdx.x;
    const int tid = threadIdx.x;
    const int lane = tid & 63;
    const int wr = (tid >> 7) & 1, wc = (tid >> 6) & 1;
    const int cr4 = (lane >> 4) * 4, cn = lane & 15;

    // ---------------- phase 0: prep (1280 jobs, grid-stride) ----------------
    {
        unsigned short (*T)[65] = (unsigned short (*)[65])smem;
        const int tr = tid >> 4, tc4 = (tid & 15) * 4;
        for (int j = bid; j < 1280; j += NBLK) {
            if (j < 1024) {  // x 64x64 tile -> xb16 (row) + xT16 (transposed)
                const int b = j >> 9, q = j & 511, lt = q >> 3, it = q & 7;
                const float* src = x + (size_t)b * LDIM * DIN +
                                   (size_t)lt * 64 * DIN + it * 64;
                unsigned short* d0 = xb + (size_t)b * LDIM * DIN +
                                     (size_t)lt * 64 * DIN + it * 64;
                unsigned short* d1 = xT + (size_t)b * DIN * LDIM +
                                     (size_t)it * 64 * LDIM + lt * 64;
#pragma unroll
                for (int p = 0; p < 4; ++p) {
                    int r = p * 16 + tr;
                    float4 v = *(const float4*)(src + (size_t)r * DIN + tc4);
                    ushort4 u = make_ushort4(f2bf(v.x), f2bf(v.y), f2bf(v.z),
                                             f2bf(v.w));
                    *(ushort4*)(d0 + (size_t)r * DIN + tc4) = u;
                    T[r][tc4 + 0] = u.x; T[r][tc4 + 1] = u.y;
                    T[r][tc4 + 2] = u.z; T[r][tc4 + 3] = u.w;
                }
                __syncthreads();
#pragma unroll
                for (int p = 0; p < 4; ++p) {
                    int c = p * 16 + tr;
                    ushort4 u = make_ushort4(T[tc4 + 0][c], T[tc4 + 1][c],
                                             T[tc4 + 2][c], T[tc4 + 3][c]);
                    *(ushort4*)(d1 + (size_t)c * LDIM + tc4) = u;
                }
                __syncthreads();
            } else {
                const int p_ = j - 1024;
                const int t = p_ & 7, job = (p_ >> 3) & 3, h = p_ >> 5;
                if (job == 0) {  // Wq[h] -> WqC (i-major, head-interleaved)
                    const float* src = Wq + (size_t)h * DIN * DK;
#pragma unroll
                    for (int p = 0; p < 4; ++p) {
                        int i = t * 64 + p * 16 + tr;
                        float4 v = *(const float4*)(src + (size_t)i * DK + tc4);
                        *(ushort4*)(WqC + (size_t)i * (HDIM * DK) + h * DK + tc4) =
                            make_ushort4(f2bf(v.x), f2bf(v.y), f2bf(v.z),
                                         f2bf(v.w));
                    }
                } else {
                    const float* src;
                    unsigned short* dst;
                    int rows, cols, r0, c0;
                    if (job == 1) {
                        src = Wk + (size_t)h * DIN * DK;
                        dst = WkT + (size_t)h * DK * DIN;
                        rows = DIN; cols = DK; r0 = t * 64; c0 = 0;
                    } else if (job == 2) {
                        src = Wv + (size_t)h * DIN * DV;
                        dst = WvT + (size_t)h * DV * DIN;
                        rows = DIN; cols = DV; r0 = t * 64; c0 = 0;
                    } else {
                        src = Wo + (size_t)h * DV * DOUT;
                        dst = WoT + (size_t)h * DOUT * DV;
                        rows = DV; cols = DOUT; r0 = 0; c0 = t * 64;
                    }
#pragma unroll
                    for (int p = 0; p < 4; ++p) {
                        int r = p * 16 + tr;
                        float4 v = *(const float4*)(src + (size_t)(r0 + r) * cols +
                                                    c0 + tc4);
                        T[r][tc4 + 0] = f2bf(v.x); T[r][tc4 + 1] = f2bf(v.y);
                        T[r][tc4 + 2] = f2bf(v.z); T[r][tc4 + 3] = f2bf(v.w);
                    }
                    __syncthreads();
#pragma unroll
                    for (int p = 0; p < 4; ++p) {
                        int c = p * 16 + tr;
                        ushort4 u = make_ushort4(T[tc4 + 0][c], T[tc4 + 1][c],
                                                 T[tc4 + 2][c], T[tc4 + 3][c]);
                        *(ushort4*)(dst + (size_t)(c0 + c) * rows + r0 + tc4) = u;
                    }
                    __syncthreads();
                }
            }
        }
    }
    gbar(bar, 0);

    // ---------------- phase 1: Gp[chunk][b] = xT xT^T slice (512 jobs) ------
    {
        const int b = bid >> 8, r = bid & 255;
        const int chunk = r >> 5, t = r & 31;
        const int i0 = (t >> 3) * 128, j0 = (t & 7) * 64;
        const bf16_t* Xb = (const bf16_t*)xT + (size_t)b * DIN * LDIM +
                           chunk * (LDIM / NCHUNK);
        float* Gc = Gp + ((size_t)chunk * BDIM + b) * DIN * DIN;
        gemm_tile<128, 64, 64>(smem, Xb, Xb, Gc, LDIM / NCHUNK, LDIM, LDIM,
                               DIN, i0, j0);
    }
    gbar(bar, 1);

    // ---------------- phase 1b: Gb = bf16(sum of 8 Gp partials) -------------
    {
        const size_t tg = (size_t)bid * 256 + tid;  // 0..131071
        const float* g0 = Gp + tg * 4;
        float4 s = *(const float4*)g0;
#pragma unroll
        for (int ch = 1; ch < NCHUNK; ++ch) {
            float4 t4 = *(const float4*)(g0 + (size_t)ch * (BDIM * DIN * DIN));
            s.x += t4.x; s.y += t4.y; s.z += t4.z; s.w += t4.w;
        }
        *(ushort4*)(Gb + tg * 4) =
            make_ushort4(f2bf(s.x), f2bf(s.y), f2bf(s.z), f2bf(s.w));
    }
    gbar(bar, 2);

    // ---------------- phase 2: gvm (128 jobs) -------------------------------
    if (bid < 128) {
        const int jt = bid & 7, h = (bid >> 3) & 7, b = bid >> 6;
        const int j0 = jt * 64;
        bf16_t* As = (bf16_t*)smem;
        bf16_t* Bs = As + 64 * 64;
        bf16_t* Vs = Bs + 64 * 64;
        bf16_t* T2s = Vs + 64 * 64;
        const bf16_t* A = (const bf16_t*)WkT + (size_t)h * DK * DIN;
        const bf16_t* Gbb = (const bf16_t*)Gb + (size_t)b * DIN * DIN;

        floatx4 acc[2][2] = {};
        for (int k0 = 0; k0 < DIN; k0 += 64) {
#pragma unroll
            for (int i = 0; i < 2; ++i) {
                int c = i * 256 + tid, m = c >> 3, kc = c & 7;
                gld_lds16(A + (size_t)m * DIN + k0 + kc * 8, As + c * 8);
                gld_lds16(Gbb + (size_t)(j0 + m) * DIN + k0 + kc * 8, Bs + c * 8);
            }
            __syncthreads();
#pragma unroll
            for (int kk = 0; kk < 64; kk += 32) {
                bf16x8 aF[2], bF[2];
#pragma unroll
                for (int f = 0; f < 2; ++f) {
                    aF[f] = *(const bf16x8*)(As + (wr * 32 + f * 16 + cn) * 64 +
                                             kk + (lane >> 4) * 8);
                    bF[f] = *(const bf16x8*)(Bs + (wc * 32 + f * 16 + cn) * 64 +
                                             kk + (lane >> 4) * 8);
                }
#pragma unroll
                for (int fm = 0; fm < 2; ++fm)
#pragma unroll
                    for (int fn = 0; fn < 2; ++fn)
                        acc[fm][fn] = __builtin_amdgcn_mfma_f32_16x16x32_bf16(
                            aF[fm], bF[fn], acc[fm][fn], 0, 0, 0);
            }
            __syncthreads();
        }

        // T2 -> LDS bf16, stage Wv j-slice
#pragma unroll
        for (int fm = 0; fm < 2; ++fm)
#pragma unroll
            for (int fn = 0; fn < 2; ++fn)
#pragma unroll
                for (int r = 0; r < 4; ++r) {
                    int m = wr * 32 + fm * 16 + cr4 + r;  // dk
                    int n = wc * 32 + fn * 16 + cn;       // j local
                    ((unsigned short*)T2s)[m * 64 + n] = f2bf(acc[fm][fn][r]);
                }
#pragma unroll
        for (int i = 0; i < 2; ++i) {
            int c = i * 256 + tid, v = c >> 3, kc = c & 7;
            gld_lds16(WvT + ((size_t)h * DV + v) * DIN + j0 + kc * 8, Vs + c * 8);
        }
        __syncthreads();

        floatx4 mm[2][2] = {};
#pragma unroll
        for (int kk = 0; kk < 64; kk += 32) {
            bf16x8 aF[2], bF[2];
#pragma unroll
            for (int f = 0; f < 2; ++f) {
                aF[f] = *(const bf16x8*)(T2s + (wr * 32 + f * 16 + cn) * 64 + kk +
                                         (lane >> 4) * 8);
                bF[f] = *(const bf16x8*)(Vs + (wc * 32 + f * 16 + cn) * 64 + kk +
                                         (lane >> 4) * 8);
            }
#pragma unroll
            for (int fm = 0; fm < 2; ++fm)
#pragma unroll
                for (int fn = 0; fn < 2; ++fn)
                    mm[fm][fn] = __builtin_amdgcn_mfma_f32_16x16x32_bf16(
                        aF[fm], bF[fn], mm[fm][fn], 0, 0, 0);
        }
        unsigned short* MpD =
            Mp + ((size_t)(jt * BDIM + b) * HDIM + h) * (DK * DV);
#pragma unroll
        for (int fm = 0; fm < 2; ++fm)
#pragma unroll
            for (int fn = 0; fn < 2; ++fn)
#pragma unroll
                for (int r = 0; r < 4; ++r) {
                    int dk = wr * 32 + fm * 16 + cr4 + r;
                    int v = wc * 32 + fn * 16 + cn;
                    MpD[dk * 64 + v] = f2bf(mm[fm][fn][r]);
                }
    }
    gbar(bar, 3);

    // ---------------- phase 3: tail (128 jobs) ------------------------------
    if (bid < 128) {
        const int it = bid & 7, ot = (bid >> 3) & 7, b = bid >> 6;
        const int i0 = it * 64, o0 = ot * 64;
        bf16_t* Aq = (bf16_t*)smem;
        bf16_t* Ws = Aq + 64 * 64;
        bf16_t* Msh = Ws + 64 * 64;
        bf16_t* PTs = Msh + 64 * 64;

        floatx4 acc[2][2] = {};
        for (int h = 0; h < HDIM; ++h) {
#pragma unroll
            for (int i = 0; i < 2; ++i) {
                int c = i * 256 + tid, m = c >> 3, kc = c & 7;
                gld_lds16(WqC + (size_t)(i0 + m) * DIN + h * 64 + kc * 8,
                          Aq + c * 8);
                gld_lds16(WoT + ((size_t)h * DOUT + o0 + m) * DV + kc * 8,
                          Ws + c * 8);
            }
            // Msh = bf16( sum over 8 jt of Mp[jt][b][h] )
#pragma unroll
            for (int i = 0; i < 2; ++i) {
                int idx = (i * 256 + tid) * 8;
                float s[8] = {0.f, 0.f, 0.f, 0.f, 0.f, 0.f, 0.f, 0.f};
#pragma unroll
                for (int p = 0; p < 8; ++p) {
                    const unsigned short* mp =
                        Mp + ((size_t)(p * BDIM + b) * HDIM + h) * (DK * DV) + idx;
                    uint4 u = *(const uint4*)mp;
                    const unsigned short* e = (const unsigned short*)&u;
#pragma unroll
                    for (int q = 0; q < 8; ++q) s[q] += bf2f(e[q]);
                }
                unsigned short o[8];
#pragma unroll
                for (int q = 0; q < 8; ++q) o[q] = f2bf(s[q]);
                *(uint4*)((unsigned short*)Msh + idx) = *(const uint4*)o;
            }
            __syncthreads();

            floatx4 pt[2][2] = {};
#pragma unroll
            for (int kk = 0; kk < 64; kk += 32) {
                bf16x8 aF[2], bF[2];
#pragma unroll
                for (int f = 0; f < 2; ++f) {
                    aF[f] = *(const bf16x8*)(Ws + (wr * 32 + f * 16 + cn) * 64 +
                                             kk + (lane >> 4) * 8);
                    bF[f] = *(const bf16x8*)(Msh + (wc * 32 + f * 16 + cn) * 64 +
                                             kk + (lane >> 4) * 8);
                }
#pragma unroll
                for (int fm = 0; fm < 2; ++fm)
#pragma unroll
                    for (int fn = 0; fn < 2; ++fn)
                        pt[fm][fn] = __builtin_amdgcn_mfma_f32_16x16x32_bf16(
                            aF[fm], bF[fn], pt[fm][fn], 0, 0, 0);
            }
#pragma unroll
            for (int fm = 0; fm < 2; ++fm)
#pragma unroll
                for (int fn = 0; fn < 2; ++fn)
#pragma unroll
                    for (int r = 0; r < 4; ++r) {
                        int m = wr * 32 + fm * 16 + cr4 + r;
                        int n = wc * 32 + fn * 16 + cn;
                        ((unsigned short*)PTs)[m * 64 + n] = f2bf(pt[fm][fn][r]);
                    }
            __syncthreads();

#pragma unroll
            for (int kk = 0; kk < 64; kk += 32) {
                bf16x8 aF[2], bF[2];
#pragma unroll
                for (int f = 0; f < 2; ++f) {
                    aF[f] = *(const bf16x8*)(PTs + (wr * 32 + f * 16 + cn) * 64 +
                                             kk + (lane >> 4) * 8);
                    bF[f] = *(const bf16x8*)(Aq + (wc * 32 + f * 16 + cn) * 64 +
                                             kk + (lane >> 4) * 8);
                }
#pragma unroll
                for (int fm = 0; fm < 2; ++fm)
#pragma unroll
                    for (int fn = 0; fn < 2; ++fn)
                        acc[fm][fn] = __builtin_amdgcn_mfma_f32_16x16x32_bf16(
                            aF[fm], bF[fn], acc[fm][fn], 0, 0, 0);
            }
            __syncthreads();
        }

        unsigned short* CTb = CT + (size_t)b * DIN * DOUT;
#pragma unroll
        for (int fm = 0; fm < 2; ++fm)
#pragma unroll
            for (int fn = 0; fn < 2; ++fn)
#pragma unroll
                for (int r = 0; r < 4; ++r) {
                    int m = wr * 32 + fm * 16 + cr4 + r;
                    int n = wc * 32 + fn * 16 + cn;
                    CTb[(size_t)(o0 + m) * DIN + i0 + n] = f2bf(acc[fm][fn][r]);
                }
    }
    gbar(bar, 4);

    // ---------------- phase 4: out = xb16 @ CT^T (512 jobs) -----------------
    {
        const int b = bid >> 8, r = bid & 255;
        const int lt = r & 63, nt = r >> 6;
        gemm_tile<64, 128, 64>(smem, (const bf16_t*)xb + (size_t)b * LDIM * DIN,
                               (const bf16_t*)CT + (size_t)b * DIN * DOUT,
                               out + (size_t)b * LDIM * DOUT, DIN, DIN, DIN,
                               DOUT, lt * 64, nt * 128);
    }
}

extern "C" void kernel_launch(void* const* d_in, const int* in_sizes, int n_in,
                              void* d_out, int out_size, void* d_ws, size_t ws_size,
                              hipStream_t stream) {
    const float* x  = (const float*)d_in[0];
    const float* Wq = (const float*)d_in[1];
    const float* Wk = (const float*)d_in[2];
    const float* Wv = (const float*)d_in[3];
    const float* Wo = (const float*)d_in[4];

    hipMemsetAsync(d_ws, 0, 256, stream);  // zero barrier counters
    k_all<<<dim3(NBLK), dim3(256), SMEM_BYTES, stream>>>(
        x, Wq, Wk, Wv, Wo, (char*)d_ws, (float*)d_out);
}

// Round 4
// 326.521 us; speedup vs baseline: 2.2525x; 2.2525x over previous
//
#include <hip/hip_runtime.h>
#include <cstdint>

// out[b] = x[b] @ C[b],  C[b] = sum_h Wq[h] M[b,h] Wo[h],  M = Wk^T (x^T x) Wv
// R14: R13's single persistent kernel with the device barrier FIXED.
// R13 post-mortem: 686us, MfmaUtil 0.6% -> ~130us per barrier, caused by
// (a) per-poll ACQUIRE loads emitting cache-invalidates, (b) per-THREAD
// __threadfence (256x512x5 L2 wb/inv ops), (c) 512 pollers hammering one
// line every ~1ns, queueing arrivals behind polls.
// Fix: one release-fence + one acquire-fence per BLOCK (thread 0 only),
// RELAXED fetch_add + RELAXED polls (no cache ops in loop), s_sleep(32)
// (~0.85us poll interval).  Phases unchanged from R13.

#define BDIM 2
#define LDIM 4096
#define DIN 512
#define HDIM 8
#define DK 64
#define DV 64
#define DOUT 512
#define NCHUNK 8
#define NBLK 512
#define SMEM_BYTES 32768

using bf16_t = __bf16;
typedef __bf16 bf16x8 __attribute__((ext_vector_type(8)));
typedef float floatx4 __attribute__((ext_vector_type(4)));

constexpr size_t OFF_XB  = 4096;
constexpr size_t OFF_XT  = OFF_XB  + (size_t)BDIM * LDIM * DIN * 2;
constexpr size_t OFF_WQC = OFF_XT  + (size_t)BDIM * LDIM * DIN * 2;
constexpr size_t OFF_WKT = OFF_WQC + (size_t)DIN * HDIM * DK * 2;
constexpr size_t OFF_WVT = OFF_WKT + (size_t)HDIM * DK * DIN * 2;
constexpr size_t OFF_WOT = OFF_WVT + (size_t)HDIM * DV * DIN * 2;
constexpr size_t OFF_CT  = OFF_WOT + (size_t)HDIM * DOUT * DV * 2;
constexpr size_t OFF_GB  = OFF_CT  + (size_t)BDIM * DIN * DOUT * 2;
constexpr size_t OFF_MP  = OFF_GB  + (size_t)BDIM * DIN * DIN * 2;
constexpr size_t OFF_GP  = OFF_MP  + (size_t)NCHUNK * BDIM * HDIM * DK * DV * 2;

__device__ __forceinline__ unsigned short f2bf(float f) {
    unsigned int u = __builtin_bit_cast(unsigned int, f);
    u += 0x7FFFu + ((u >> 16) & 1u);
    return (unsigned short)(u >> 16);
}

__device__ __forceinline__ float bf2f(unsigned short u) {
    unsigned int v = ((unsigned int)u) << 16;
    return __builtin_bit_cast(float, v);
}

__device__ __forceinline__ void gld_lds16(const void* g, void* l) {
    __builtin_amdgcn_global_load_lds(
        (const __attribute__((address_space(1))) void*)g,
        (__attribute__((address_space(3))) void*)l, 16, 0, 0);
}

// Device-wide barrier, monotonic counter per call site, host-memset to 0.
// Fences: exactly one release + one acquire per BLOCK (thread 0).  Polls
// are RELAXED (no cache maintenance) at ~0.85us intervals (s_sleep(32)).
__device__ __forceinline__ void gbar(unsigned* bar, int idx) {
    __syncthreads();
    if (threadIdx.x == 0) {
        __builtin_amdgcn_fence(__ATOMIC_RELEASE, "agent");
        __hip_atomic_fetch_add(bar + idx, 1u, __ATOMIC_RELAXED,
                               __HIP_MEMORY_SCOPE_AGENT);
        while (__hip_atomic_load(bar + idx, __ATOMIC_RELAXED,
                                 __HIP_MEMORY_SCOPE_AGENT) < (unsigned)NBLK)
            __builtin_amdgcn_s_sleep(32);
        __builtin_amdgcn_fence(__ATOMIC_ACQUIRE, "agent");
    }
    __syncthreads();
}

// ---------------- TN MFMA GEMM tile, fp32 store ----------------
// C[m][n] = sum_k A[m][k] * B[n][k]
template <int BM, int BN, int BK>
__device__ __forceinline__ void gemm_tile(char* smem, const bf16_t* A,
                                          const bf16_t* B, float* Cp, int K,
                                          int lda, int ldb, int ldc, int tm,
                                          int tn) {
    constexpr int WM = BM / 2, WN = BN / 2;
    constexpr int FM = WM / 16, FN = WN / 16;
    constexpr int CPR = BK / 8;
    bf16_t* As = (bf16_t*)smem;
    bf16_t* Bs = As + BM * BK;
    const int tid = threadIdx.x;
    const int lane = tid & 63;
    const int wr = (tid >> 7) & 1;
    const int wc = (tid >> 6) & 1;

    A += (size_t)tm * lda;
    B += (size_t)tn * ldb;

    floatx4 acc[FM][FN] = {};

    for (int k0 = 0; k0 < K; k0 += BK) {
#pragma unroll
        for (int i = 0; i < (BM * CPR) / 256; ++i) {
            int c = i * 256 + tid;
            int m = c / CPR, kc = c % CPR;
            gld_lds16(A + (size_t)m * lda + k0 + kc * 8, As + c * 8);
        }
#pragma unroll
        for (int i = 0; i < (BN * CPR) / 256; ++i) {
            int c = i * 256 + tid;
            int m = c / CPR, kc = c % CPR;
            gld_lds16(B + (size_t)m * ldb + k0 + kc * 8, Bs + c * 8);
        }
        __syncthreads();

#pragma unroll
        for (int kk = 0; kk < BK; kk += 32) {
            bf16x8 aF[FM], bF[FN];
#pragma unroll
            for (int fm = 0; fm < FM; ++fm)
                aF[fm] = *(const bf16x8*)(As + (wr * WM + fm * 16 + (lane & 15)) * BK +
                                          kk + (lane >> 4) * 8);
#pragma unroll
            for (int fn = 0; fn < FN; ++fn)
                bF[fn] = *(const bf16x8*)(Bs + (wc * WN + fn * 16 + (lane & 15)) * BK +
                                          kk + (lane >> 4) * 8);
#pragma unroll
            for (int fm = 0; fm < FM; ++fm)
#pragma unroll
                for (int fn = 0; fn < FN; ++fn)
                    acc[fm][fn] = __builtin_amdgcn_mfma_f32_16x16x32_bf16(
                        aF[fm], bF[fn], acc[fm][fn], 0, 0, 0);
        }
        __syncthreads();
    }

    const int cr4 = (lane >> 4) * 4;
    const int cn = lane & 15;
#pragma unroll
    for (int fm = 0; fm < FM; ++fm)
#pragma unroll
        for (int fn = 0; fn < FN; ++fn)
#pragma unroll
            for (int r = 0; r < 4; ++r) {
                int m = tm + wr * WM + fm * 16 + cr4 + r;
                int n = tn + wc * WN + fn * 16 + cn;
                Cp[(size_t)m * ldc + n] = acc[fm][fn][r];
            }
}

__global__ __launch_bounds__(256, 2) void k_all(
    const float* __restrict__ x, const float* __restrict__ Wq,
    const float* __restrict__ Wk, const float* __restrict__ Wv,
    const float* __restrict__ Wo, char* __restrict__ ws,
    float* __restrict__ out) {
    extern __shared__ __align__(16) char smem[];
    unsigned* bar = (unsigned*)ws;
    unsigned short* xb  = (unsigned short*)(ws + OFF_XB);
    unsigned short* xT  = (unsigned short*)(ws + OFF_XT);
    unsigned short* WqC = (unsigned short*)(ws + OFF_WQC);
    unsigned short* WkT = (unsigned short*)(ws + OFF_WKT);
    unsigned short* WvT = (unsigned short*)(ws + OFF_WVT);
    unsigned short* WoT = (unsigned short*)(ws + OFF_WOT);
    unsigned short* CT  = (unsigned short*)(ws + OFF_CT);
    unsigned short* Gb  = (unsigned short*)(ws + OFF_GB);
    unsigned short* Mp  = (unsigned short*)(ws + OFF_MP);
    float* Gp = (float*)(ws + OFF_GP);

    const int bid = blockIdx.x;
    const int tid = threadIdx.x;
    const int lane = tid & 63;
    const int wr = (tid >> 7) & 1, wc = (tid >> 6) & 1;
    const int cr4 = (lane >> 4) * 4, cn = lane & 15;

    // ---------------- phase 0: prep (1280 jobs, grid-stride) ----------------
    {
        unsigned short (*T)[65] = (unsigned short (*)[65])smem;
        const int tr = tid >> 4, tc4 = (tid & 15) * 4;
        for (int j = bid; j < 1280; j += NBLK) {
            if (j < 1024) {  // x 64x64 tile -> xb16 (row) + xT16 (transposed)
                const int b = j >> 9, q = j & 511, lt = q >> 3, it = q & 7;
                const float* src = x + (size_t)b * LDIM * DIN +
                                   (size_t)lt * 64 * DIN + it * 64;
                unsigned short* d0 = xb + (size_t)b * LDIM * DIN +
                                     (size_t)lt * 64 * DIN + it * 64;
                unsigned short* d1 = xT + (size_t)b * DIN * LDIM +
                                     (size_t)it * 64 * LDIM + lt * 64;
#pragma unroll
                for (int p = 0; p < 4; ++p) {
                    int r = p * 16 + tr;
                    float4 v = *(const float4*)(src + (size_t)r * DIN + tc4);
                    ushort4 u = make_ushort4(f2bf(v.x), f2bf(v.y), f2bf(v.z),
                                             f2bf(v.w));
                    *(ushort4*)(d0 + (size_t)r * DIN + tc4) = u;
                    T[r][tc4 + 0] = u.x; T[r][tc4 + 1] = u.y;
                    T[r][tc4 + 2] = u.z; T[r][tc4 + 3] = u.w;
                }
                __syncthreads();
#pragma unroll
                for (int p = 0; p < 4; ++p) {
                    int c = p * 16 + tr;
                    ushort4 u = make_ushort4(T[tc4 + 0][c], T[tc4 + 1][c],
                                             T[tc4 + 2][c], T[tc4 + 3][c]);
                    *(ushort4*)(d1 + (size_t)c * LDIM + tc4) = u;
                }
                __syncthreads();
            } else {
                const int p_ = j - 1024;
                const int t = p_ & 7, job = (p_ >> 3) & 3, h = p_ >> 5;
                if (job == 0) {  // Wq[h] -> WqC (i-major, head-interleaved)
                    const float* src = Wq + (size_t)h * DIN * DK;
#pragma unroll
                    for (int p = 0; p < 4; ++p) {
                        int i = t * 64 + p * 16 + tr;
                        float4 v = *(const float4*)(src + (size_t)i * DK + tc4);
                        *(ushort4*)(WqC + (size_t)i * (HDIM * DK) + h * DK + tc4) =
                            make_ushort4(f2bf(v.x), f2bf(v.y), f2bf(v.z),
                                         f2bf(v.w));
                    }
                } else {
                    const float* src;
                    unsigned short* dst;
                    int rows, cols, r0, c0;
                    if (job == 1) {
                        src = Wk + (size_t)h * DIN * DK;
                        dst = WkT + (size_t)h * DK * DIN;
                        rows = DIN; cols = DK; r0 = t * 64; c0 = 0;
                    } else if (job == 2) {
                        src = Wv + (size_t)h * DIN * DV;
                        dst = WvT + (size_t)h * DV * DIN;
                        rows = DIN; cols = DV; r0 = t * 64; c0 = 0;
                    } else {
                        src = Wo + (size_t)h * DV * DOUT;
                        dst = WoT + (size_t)h * DOUT * DV;
                        rows = DV; cols = DOUT; r0 = 0; c0 = t * 64;
                    }
#pragma unroll
                    for (int p = 0; p < 4; ++p) {
                        int r = p * 16 + tr;
                        float4 v = *(const float4*)(src + (size_t)(r0 + r) * cols +
                                                    c0 + tc4);
                        T[r][tc4 + 0] = f2bf(v.x); T[r][tc4 + 1] = f2bf(v.y);
                        T[r][tc4 + 2] = f2bf(v.z); T[r][tc4 + 3] = f2bf(v.w);
                    }
                    __syncthreads();
#pragma unroll
                    for (int p = 0; p < 4; ++p) {
                        int c = p * 16 + tr;
                        ushort4 u = make_ushort4(T[tc4 + 0][c], T[tc4 + 1][c],
                                                 T[tc4 + 2][c], T[tc4 + 3][c]);
                        *(ushort4*)(dst + (size_t)(c0 + c) * rows + r0 + tc4) = u;
                    }
                    __syncthreads();
                }
            }
        }
    }
    gbar(bar, 0);

    // ---------------- phase 1: Gp[chunk][b] = xT xT^T slice (512 jobs) ------
    {
        const int b = bid >> 8, r = bid & 255;
        const int chunk = r >> 5, t = r & 31;
        const int i0 = (t >> 3) * 128, j0 = (t & 7) * 64;
        const bf16_t* Xb = (const bf16_t*)xT + (size_t)b * DIN * LDIM +
                           chunk * (LDIM / NCHUNK);
        float* Gc = Gp + ((size_t)chunk * BDIM + b) * DIN * DIN;
        gemm_tile<128, 64, 64>(smem, Xb, Xb, Gc, LDIM / NCHUNK, LDIM, LDIM,
                               DIN, i0, j0);
    }
    gbar(bar, 1);

    // ---------------- phase 1b: Gb = bf16(sum of 8 Gp partials) -------------
    {
        const size_t tg = (size_t)bid * 256 + tid;  // 0..131071
        const float* g0 = Gp + tg * 4;
        float4 s = *(const float4*)g0;
#pragma unroll
        for (int ch = 1; ch < NCHUNK; ++ch) {
            float4 t4 = *(const float4*)(g0 + (size_t)ch * (BDIM * DIN * DIN));
            s.x += t4.x; s.y += t4.y; s.z += t4.z; s.w += t4.w;
        }
        *(ushort4*)(Gb + tg * 4) =
            make_ushort4(f2bf(s.x), f2bf(s.y), f2bf(s.z), f2bf(s.w));
    }
    gbar(bar, 2);

    // ---------------- phase 2: gvm (128 jobs) -------------------------------
    if (bid < 128) {
        const int jt = bid & 7, h = (bid >> 3) & 7, b = bid >> 6;
        const int j0 = jt * 64;
        bf16_t* As = (bf16_t*)smem;
        bf16_t* Bs = As + 64 * 64;
        bf16_t* Vs = Bs + 64 * 64;
        bf16_t* T2s = Vs + 64 * 64;
        const bf16_t* A = (const bf16_t*)WkT + (size_t)h * DK * DIN;
        const bf16_t* Gbb = (const bf16_t*)Gb + (size_t)b * DIN * DIN;

        floatx4 acc[2][2] = {};
        for (int k0 = 0; k0 < DIN; k0 += 64) {
#pragma unroll
            for (int i = 0; i < 2; ++i) {
                int c = i * 256 + tid, m = c >> 3, kc = c & 7;
                gld_lds16(A + (size_t)m * DIN + k0 + kc * 8, As + c * 8);
                gld_lds16(Gbb + (size_t)(j0 + m) * DIN + k0 + kc * 8, Bs + c * 8);
            }
            __syncthreads();
#pragma unroll
            for (int kk = 0; kk < 64; kk += 32) {
                bf16x8 aF[2], bF[2];
#pragma unroll
                for (int f = 0; f < 2; ++f) {
                    aF[f] = *(const bf16x8*)(As + (wr * 32 + f * 16 + cn) * 64 +
                                             kk + (lane >> 4) * 8);
                    bF[f] = *(const bf16x8*)(Bs + (wc * 32 + f * 16 + cn) * 64 +
                                             kk + (lane >> 4) * 8);
                }
#pragma unroll
                for (int fm = 0; fm < 2; ++fm)
#pragma unroll
                    for (int fn = 0; fn < 2; ++fn)
                        acc[fm][fn] = __builtin_amdgcn_mfma_f32_16x16x32_bf16(
                            aF[fm], bF[fn], acc[fm][fn], 0, 0, 0);
            }
            __syncthreads();
        }

        // T2 -> LDS bf16, stage Wv j-slice
#pragma unroll
        for (int fm = 0; fm < 2; ++fm)
#pragma unroll
            for (int fn = 0; fn < 2; ++fn)
#pragma unroll
                for (int r = 0; r < 4; ++r) {
                    int m = wr * 32 + fm * 16 + cr4 + r;  // dk
                    int n = wc * 32 + fn * 16 + cn;       // j local
                    ((unsigned short*)T2s)[m * 64 + n] = f2bf(acc[fm][fn][r]);
                }
#pragma unroll
        for (int i = 0; i < 2; ++i) {
            int c = i * 256 + tid, v = c >> 3, kc = c & 7;
            gld_lds16(WvT + ((size_t)h * DV + v) * DIN + j0 + kc * 8, Vs + c * 8);
        }
        __syncthreads();

        floatx4 mm[2][2] = {};
#pragma unroll
        for (int kk = 0; kk < 64; kk += 32) {
            bf16x8 aF[2], bF[2];
#pragma unroll
            for (int f = 0; f < 2; ++f) {
                aF[f] = *(const bf16x8*)(T2s + (wr * 32 + f * 16 + cn) * 64 + kk +
                                         (lane >> 4) * 8);
                bF[f] = *(const bf16x8*)(Vs + (wc * 32 + f * 16 + cn) * 64 + kk +
                                         (lane >> 4) * 8);
            }
#pragma unroll
            for (int fm = 0; fm < 2; ++fm)
#pragma unroll
                for (int fn = 0; fn < 2; ++fn)
                    mm[fm][fn] = __builtin_amdgcn_mfma_f32_16x16x32_bf16(
                        aF[fm], bF[fn], mm[fm][fn], 0, 0, 0);
        }
        unsigned short* MpD =
            Mp + ((size_t)(jt * BDIM + b) * HDIM + h) * (DK * DV);
#pragma unroll
        for (int fm = 0; fm < 2; ++fm)
#pragma unroll
            for (int fn = 0; fn < 2; ++fn)
#pragma unroll
                for (int r = 0; r < 4; ++r) {
                    int dk = wr * 32 + fm * 16 + cr4 + r;
                    int v = wc * 32 + fn * 16 + cn;
                    MpD[dk * 64 + v] = f2bf(mm[fm][fn][r]);
                }
    }
    gbar(bar, 3);

    // ---------------- phase 3: tail (128 jobs) ------------------------------
    if (bid < 128) {
        const int it = bid & 7, ot = (bid >> 3) & 7, b = bid >> 6;
        const int i0 = it * 64, o0 = ot * 64;
        bf16_t* Aq = (bf16_t*)smem;
        bf16_t* Ws = Aq + 64 * 64;
        bf16_t* Msh = Ws + 64 * 64;
        bf16_t* PTs = Msh + 64 * 64;

        floatx4 acc[2][2] = {};
        for (int h = 0; h < HDIM; ++h) {
#pragma unroll
            for (int i = 0; i < 2; ++i) {
                int c = i * 256 + tid, m = c >> 3, kc = c & 7;
                gld_lds16(WqC + (size_t)(i0 + m) * DIN + h * 64 + kc * 8,
                          Aq + c * 8);
                gld_lds16(WoT + ((size_t)h * DOUT + o0 + m) * DV + kc * 8,
                          Ws + c * 8);
            }
            // Msh = bf16( sum over 8 jt of Mp[jt][b][h] )
#pragma unroll
            for (int i = 0; i < 2; ++i) {
                int idx = (i * 256 + tid) * 8;
                float s[8] = {0.f, 0.f, 0.f, 0.f, 0.f, 0.f, 0.f, 0.f};
#pragma unroll
                for (int p = 0; p < 8; ++p) {
                    const unsigned short* mp =
                        Mp + ((size_t)(p * BDIM + b) * HDIM + h) * (DK * DV) + idx;
                    uint4 u = *(const uint4*)mp;
                    const unsigned short* e = (const unsigned short*)&u;
#pragma unroll
                    for (int q = 0; q < 8; ++q) s[q] += bf2f(e[q]);
                }
                unsigned short o[8];
#pragma unroll
                for (int q = 0; q < 8; ++q) o[q] = f2bf(s[q]);
                *(uint4*)((unsigned short*)Msh + idx) = *(const uint4*)o;
            }
            __syncthreads();

            floatx4 pt[2][2] = {};
#pragma unroll
            for (int kk = 0; kk < 64; kk += 32) {
                bf16x8 aF[2], bF[2];
#pragma unroll
                for (int f = 0; f < 2; ++f) {
                    aF[f] = *(const bf16x8*)(Ws + (wr * 32 + f * 16 + cn) * 64 +
                                             kk + (lane >> 4) * 8);
                    bF[f] = *(const bf16x8*)(Msh + (wc * 32 + f * 16 + cn) * 64 +
                                             kk + (lane >> 4) * 8);
                }
#pragma unroll
                for (int fm = 0; fm < 2; ++fm)
#pragma unroll
                    for (int fn = 0; fn < 2; ++fn)
                        pt[fm][fn] = __builtin_amdgcn_mfma_f32_16x16x32_bf16(
                            aF[fm], bF[fn], pt[fm][fn], 0, 0, 0);
            }
#pragma unroll
            for (int fm = 0; fm < 2; ++fm)
#pragma unroll
                for (int fn = 0; fn < 2; ++fn)
#pragma unroll
                    for (int r = 0; r < 4; ++r) {
                        int m = wr * 32 + fm * 16 + cr4 + r;
                        int n = wc * 32 + fn * 16 + cn;
                        ((unsigned short*)PTs)[m * 64 + n] = f2bf(pt[fm][fn][r]);
                    }
            __syncthreads();

#pragma unroll
            for (int kk = 0; kk < 64; kk += 32) {
                bf16x8 aF[2], bF[2];
#pragma unroll
                for (int f = 0; f < 2; ++f) {
                    aF[f] = *(const bf16x8*)(PTs + (wr * 32 + f * 16 + cn) * 64 +
                                             kk + (lane >> 4) * 8);
                    bF[f] = *(const bf16x8*)(Aq + (wc * 32 + f * 16 + cn) * 64 +
                                             kk + (lane >> 4) * 8);
                }
#pragma unroll
                for (int fm = 0; fm < 2; ++fm)
#pragma unroll
                    for (int fn = 0; fn < 2; ++fn)
                        acc[fm][fn] = __builtin_amdgcn_mfma_f32_16x16x32_bf16(
                            aF[fm], bF[fn], acc[fm][fn], 0, 0, 0);
            }
            __syncthreads();
        }

        unsigned short* CTb = CT + (size_t)b * DIN * DOUT;
#pragma unroll
        for (int fm = 0; fm < 2; ++fm)
#pragma unroll
            for (int fn = 0; fn < 2; ++fn)
#pragma unroll
                for (int r = 0; r < 4; ++r) {
                    int m = wr * 32 + fm * 16 + cr4 + r;
                    int n = wc * 32 + fn * 16 + cn;
                    CTb[(size_t)(o0 + m) * DIN + i0 + n] = f2bf(acc[fm][fn][r]);
                }
    }
    gbar(bar, 4);

    // ---------------- phase 4: out = xb16 @ CT^T (512 jobs) -----------------
    {
        const int b = bid >> 8, r = bid & 255;
        const int lt = r & 63, nt = r >> 6;
        gemm_tile<64, 128, 64>(smem, (const bf16_t*)xb + (size_t)b * LDIM * DIN,
                               (const bf16_t*)CT + (size_t)b * DIN * DOUT,
                               out + (size_t)b * LDIM * DOUT, DIN, DIN, DIN,
                               DOUT, lt * 64, nt * 128);
    }
}

extern "C" void kernel_launch(void* const* d_in, const int* in_sizes, int n_in,
                              void* d_out, int out_size, void* d_ws, size_t ws_size,
                              hipStream_t stream) {
    const float* x  = (const float*)d_in[0];
    const float* Wq = (const float*)d_in[1];
    const float* Wk = (const float*)d_in[2];
    const float* Wv = (const float*)d_in[3];
    const float* Wo = (const float*)d_in[4];

    hipMemsetAsync(d_ws, 0, 256, stream);  // zero barrier counters
    k_all<<<dim3(NBLK), dim3(256), SMEM_BYTES, stream>>>(
        x, Wq, Wk, Wv, Wo, (char*)d_ws, (float*)d_out);
}

// Round 5
// 163.566 us; speedup vs baseline: 4.4966x; 1.9963x over previous
//
#include <hip/hip_runtime.h>
#include <cstdint>

// out[b] = x[b] @ C[b],  C[b] = sum_h Wq[h] M[b,h] Wo[h],  M = Wk^T (x^T x) Wv
// R15: 3 launches, NO software device barriers.
// R14 measured SW grid-sync at ~44us/barrier (per-block agent fences =
// 512 serialized L2 wb/inv walks); a kernel launch boundary does the same
// coherence in HW for ~14.5us.  Cost model: dur = 45 (harness fill) +
// 14.5*n_dispatch + work.  So: minimize dispatches AND work.
//   K1 prep: x->xb16+xT, W transposes, zero G/M/counter.
//   K2 main: xtx (split-K=4, fp32 atomicAdd into G: HW-coherent, no fence)
//            + Q' = x.Wq  tiles.  Last-32-finisher gate (one system-scope
//            counter, ~2us spin) runs mid: T2=Wk^T G, M += T2 Wv (atomic).
//   K3 out': per 128x128 tile, loop h: P_h = M.Wo (LDS, transposed),
//            out += Q'_h . P_h^T.   (tail/CT kernel eliminated.)

#define BDIM 2
#define LDIM 4096
#define DIN 512
#define HDIM 8
#define DK 64
#define DV 64
#define DOUT 512
#define NXTX 512
#define NMID 32
#define SMEM_MAIN 34816

using bf16_t = __bf16;
typedef __bf16 bf16x8 __attribute__((ext_vector_type(8)));
typedef float floatx4 __attribute__((ext_vector_type(4)));

constexpr size_t OFF_XB  = 4096;
constexpr size_t OFF_XT  = OFF_XB  + (size_t)BDIM * LDIM * DIN * 2;
constexpr size_t OFF_WQT = OFF_XT  + (size_t)BDIM * LDIM * DIN * 2;
constexpr size_t OFF_WKT = OFF_WQT + (size_t)HDIM * DK * DIN * 2;
constexpr size_t OFF_WVT = OFF_WKT + (size_t)HDIM * DK * DIN * 2;
constexpr size_t OFF_WOT = OFF_WVT + (size_t)HDIM * DV * DIN * 2;
constexpr size_t OFF_QP  = OFF_WOT + (size_t)HDIM * DOUT * DV * 2;
constexpr size_t OFF_G32 = OFF_QP  + (size_t)BDIM * LDIM * DIN * 2;
constexpr size_t OFF_M32 = OFF_G32 + (size_t)BDIM * DIN * DIN * 4;

__device__ __forceinline__ unsigned short f2bf(float f) {
    unsigned int u = __builtin_bit_cast(unsigned int, f);
    u += 0x7FFFu + ((u >> 16) & 1u);
    return (unsigned short)(u >> 16);
}

__device__ __forceinline__ void gld_lds16(const void* g, void* l) {
    __builtin_amdgcn_global_load_lds(
        (const __attribute__((address_space(1))) void*)g,
        (__attribute__((address_space(3))) void*)l, 16, 0, 0);
}

// ---------------- TN MFMA GEMM tile on caller-provided LDS ----------------
// C[m][n] = sum_k A[m][k] * B[n][k].  OUT_MODE: 1 = bf16 store, 2 = fp32
// atomicAdd.
template <int BM, int BN, int BK, int OUT_MODE>
__device__ __forceinline__ void gemm_tn(char* smem, const bf16_t* A,
                                        const bf16_t* B, void* Cp, int K,
                                        int lda, int ldb, int ldc, int tm,
                                        int tn) {
    constexpr int WM = BM / 2, WN = BN / 2;
    constexpr int FM = WM / 16, FN = WN / 16;
    constexpr int CPR = BK / 8;
    bf16_t* As = (bf16_t*)smem;
    bf16_t* Bs = As + BM * BK;
    const int tid = threadIdx.x;
    const int lane = tid & 63;
    const int wr = (tid >> 7) & 1;
    const int wc = (tid >> 6) & 1;

    A += (size_t)tm * lda;
    B += (size_t)tn * ldb;

    floatx4 acc[FM][FN] = {};

    for (int k0 = 0; k0 < K; k0 += BK) {
#pragma unroll
        for (int i = 0; i < (BM * CPR) / 256; ++i) {
            int c = i * 256 + tid;
            int m = c / CPR, kc = c % CPR;
            gld_lds16(A + (size_t)m * lda + k0 + kc * 8, As + c * 8);
        }
#pragma unroll
        for (int i = 0; i < (BN * CPR) / 256; ++i) {
            int c = i * 256 + tid;
            int m = c / CPR, kc = c % CPR;
            gld_lds16(B + (size_t)m * ldb + k0 + kc * 8, Bs + c * 8);
        }
        __syncthreads();

#pragma unroll
        for (int kk = 0; kk < BK; kk += 32) {
            bf16x8 aF[FM], bF[FN];
#pragma unroll
            for (int fm = 0; fm < FM; ++fm)
                aF[fm] = *(const bf16x8*)(As + (wr * WM + fm * 16 + (lane & 15)) * BK +
                                          kk + (lane >> 4) * 8);
#pragma unroll
            for (int fn = 0; fn < FN; ++fn)
                bF[fn] = *(const bf16x8*)(Bs + (wc * WN + fn * 16 + (lane & 15)) * BK +
                                          kk + (lane >> 4) * 8);
#pragma unroll
            for (int fm = 0; fm < FM; ++fm)
#pragma unroll
                for (int fn = 0; fn < FN; ++fn)
                    acc[fm][fn] = __builtin_amdgcn_mfma_f32_16x16x32_bf16(
                        aF[fm], bF[fn], acc[fm][fn], 0, 0, 0);
        }
        __syncthreads();
    }

    const int cr4 = (lane >> 4) * 4;
    const int cn = lane & 15;
#pragma unroll
    for (int fm = 0; fm < FM; ++fm)
#pragma unroll
        for (int fn = 0; fn < FN; ++fn)
#pragma unroll
            for (int r = 0; r < 4; ++r) {
                int m = tm + wr * WM + fm * 16 + cr4 + r;
                int n = tn + wc * WN + fn * 16 + cn;
                size_t idx = (size_t)m * ldc + n;
                if (OUT_MODE == 1)
                    ((unsigned short*)Cp)[idx] = f2bf(acc[fm][fn][r]);
                else
                    atomicAdd((float*)Cp + idx, acc[fm][fn][r]);
            }
}

// ---------------- K1: prep ----------------
// bids: [0,1024) x->xb16+xT | [1024,1280) W transposes | [1280,1408) zero G
//       | [1408,1416) zero M (+counter)
__global__ __launch_bounds__(256) void k_prep(
    const float* __restrict__ x, const float* __restrict__ Wq,
    const float* __restrict__ Wk, const float* __restrict__ Wv,
    const float* __restrict__ Wo, char* __restrict__ ws) {
    __shared__ unsigned short T[64][65];
    unsigned short* xb  = (unsigned short*)(ws + OFF_XB);
    unsigned short* xT  = (unsigned short*)(ws + OFF_XT);
    unsigned short* WqT = (unsigned short*)(ws + OFF_WQT);
    unsigned short* WkT = (unsigned short*)(ws + OFF_WKT);
    unsigned short* WvT = (unsigned short*)(ws + OFF_WVT);
    unsigned short* WoT = (unsigned short*)(ws + OFF_WOT);
    float* G32 = (float*)(ws + OFF_G32);
    float* M32 = (float*)(ws + OFF_M32);

    const int tid = threadIdx.x;
    const int tr = tid >> 4, tc4 = (tid & 15) * 4;
    const int j = blockIdx.x;

    if (j < 1024) {  // x 64x64 tile -> xb16 (row-major) + xT (transposed)
        const int b = j >> 9, q = j & 511, lt = q >> 3, it = q & 7;
        const float* src = x + (size_t)b * LDIM * DIN + (size_t)lt * 64 * DIN +
                           it * 64;
        unsigned short* d0 = xb + (size_t)b * LDIM * DIN +
                             (size_t)lt * 64 * DIN + it * 64;
        unsigned short* d1 = xT + (size_t)b * DIN * LDIM +
                             (size_t)it * 64 * LDIM + lt * 64;
#pragma unroll
        for (int p = 0; p < 4; ++p) {
            int r = p * 16 + tr;
            float4 v = *(const float4*)(src + (size_t)r * DIN + tc4);
            ushort4 u = make_ushort4(f2bf(v.x), f2bf(v.y), f2bf(v.z), f2bf(v.w));
            *(ushort4*)(d0 + (size_t)r * DIN + tc4) = u;
            T[r][tc4 + 0] = u.x; T[r][tc4 + 1] = u.y;
            T[r][tc4 + 2] = u.z; T[r][tc4 + 3] = u.w;
        }
        __syncthreads();
#pragma unroll
        for (int p = 0; p < 4; ++p) {
            int c = p * 16 + tr;
            ushort4 u = make_ushort4(T[tc4 + 0][c], T[tc4 + 1][c], T[tc4 + 2][c],
                                     T[tc4 + 3][c]);
            *(ushort4*)(d1 + (size_t)c * LDIM + tc4) = u;
        }
        return;
    }
    if (j < 1280) {  // weight transposes -> bf16, k-contiguous layouts
        const int q = j - 1024;
        const int t = q & 7, h = (q >> 3) & 7, typ = q >> 6;
        const float* src;
        unsigned short* dst;
        int rows, cols, r0, c0;
        if (typ == 0) { src = Wq + (size_t)h * DIN * DK; dst = WqT + (size_t)h * DK * DIN;
                        rows = DIN; cols = DK; r0 = t * 64; c0 = 0; }
        else if (typ == 1) { src = Wk + (size_t)h * DIN * DK; dst = WkT + (size_t)h * DK * DIN;
                        rows = DIN; cols = DK; r0 = t * 64; c0 = 0; }
        else if (typ == 2) { src = Wv + (size_t)h * DIN * DV; dst = WvT + (size_t)h * DV * DIN;
                        rows = DIN; cols = DV; r0 = t * 64; c0 = 0; }
        else { src = Wo + (size_t)h * DV * DOUT; dst = WoT + (size_t)h * DOUT * DV;
                        rows = DV; cols = DOUT; r0 = 0; c0 = t * 64; }
#pragma unroll
        for (int p = 0; p < 4; ++p) {
            int r = p * 16 + tr;
            float4 v = *(const float4*)(src + (size_t)(r0 + r) * cols + c0 + tc4);
            T[r][tc4 + 0] = f2bf(v.x); T[r][tc4 + 1] = f2bf(v.y);
            T[r][tc4 + 2] = f2bf(v.z); T[r][tc4 + 3] = f2bf(v.w);
        }
        __syncthreads();
#pragma unroll
        for (int p = 0; p < 4; ++p) {
            int c = p * 16 + tr;
            ushort4 u = make_ushort4(T[tc4 + 0][c], T[tc4 + 1][c], T[tc4 + 2][c],
                                     T[tc4 + 3][c]);
            *(ushort4*)(dst + (size_t)(c0 + c) * rows + r0 + tc4) = u;
        }
        return;
    }
    if (j < 1408) {  // zero G32 (2x512x512 fp32)
        float* g = G32 + (size_t)(j - 1280) * 8192 + tid * 32;
        float4 z = make_float4(0.f, 0.f, 0.f, 0.f);
#pragma unroll
        for (int q = 0; q < 8; ++q) *(float4*)(g + q * 4) = z;
        return;
    }
    {  // zero M32 (65536 fp32) + done-counter
        float* m = M32 + (size_t)(j - 1408) * 8192 + tid * 32;
        float4 z = make_float4(0.f, 0.f, 0.f, 0.f);
#pragma unroll
        for (int q = 0; q < 8; ++q) *(float4*)(m + q * 4) = z;
        if (j == 1408 && tid == 0) *(unsigned*)ws = 0u;
    }
}

// ---------------- mid job (runs inside K2, last NMID xtx finishers) -------
// T2[dk][j] = sum_i WkT[h][dk][i] * G[b][j][i]  (G symmetric, atomically
// built, coherent at IF$; first-touch plain reads are safe post-launch-inv)
// M32[b,h] += T2 . WvT[h]   (fp32 atomicAdd)
__device__ void mid_job(int id, char* smem, const bf16_t* WkT,
                        const bf16_t* WvT, const float* G32, float* M32) {
    const int tid = threadIdx.x, lane = tid & 63;
    const int wr = (tid >> 7) & 1, wc = (tid >> 6) & 1;
    const int cr4 = (lane >> 4) * 4, cn = lane & 15;
    const int h = id & 7, b = (id >> 3) & 1, jh = (id >> 4) & 1;
    bf16_t* As  = (bf16_t*)smem;                 // 64x64
    bf16_t* Bs  = (bf16_t*)(smem + 8192);        // 64x64
    bf16_t* T2s = (bf16_t*)(smem + 16384);       // [64][72]
    bf16_t* Vs  = (bf16_t*)(smem + 25600);       // 64x64
    const bf16_t* Ah = WkT + (size_t)h * DK * DIN;
    const bf16_t* Vh = WvT + (size_t)h * DV * DIN;
    const float* Gb = G32 + (size_t)b * DIN * DIN;

    floatx4 accM[2][2] = {};
    for (int jt = 0; jt < 4; ++jt) {
        const int j0 = jh * 256 + jt * 64;
        floatx4 accT[2][2] = {};
        for (int k0 = 0; k0 < DIN; k0 += 64) {
#pragma unroll
            for (int i = 0; i < 2; ++i) {
                int c = i * 256 + tid, m = c >> 3, kc = c & 7;
                gld_lds16(Ah + (size_t)m * DIN + k0 + kc * 8, As + c * 8);
            }
#pragma unroll
            for (int i = 0; i < 2; ++i) {
                int c = i * 256 + tid, n = c >> 3, kc = c & 7;
                const float* g = Gb + (size_t)(j0 + n) * DIN + k0 + kc * 8;
                float4 v0 = *(const float4*)g;
                float4 v1 = *(const float4*)(g + 4);
                unsigned short o[8] = {f2bf(v0.x), f2bf(v0.y), f2bf(v0.z),
                                       f2bf(v0.w), f2bf(v1.x), f2bf(v1.y),
                                       f2bf(v1.z), f2bf(v1.w)};
                *(uint4*)((unsigned short*)Bs + (size_t)c * 8) = *(const uint4*)o;
            }
            __syncthreads();
#pragma unroll
            for (int kk = 0; kk < 64; kk += 32) {
                bf16x8 aF[2], bF[2];
#pragma unroll
                for (int f = 0; f < 2; ++f) {
                    aF[f] = *(const bf16x8*)(As + (wr * 32 + f * 16 + cn) * 64 +
                                             kk + (lane >> 4) * 8);
                    bF[f] = *(const bf16x8*)(Bs + (wc * 32 + f * 16 + cn) * 64 +
                                             kk + (lane >> 4) * 8);
                }
#pragma unroll
                for (int fm = 0; fm < 2; ++fm)
#pragma unroll
                    for (int fn = 0; fn < 2; ++fn)
                        accT[fm][fn] = __builtin_amdgcn_mfma_f32_16x16x32_bf16(
                            aF[fm], bF[fn], accT[fm][fn], 0, 0, 0);
            }
            __syncthreads();
        }
        // accT -> T2s [dk][j] (pad 72), stage Wv j-slice
#pragma unroll
        for (int fm = 0; fm < 2; ++fm)
#pragma unroll
            for (int fn = 0; fn < 2; ++fn)
#pragma unroll
                for (int r = 0; r < 4; ++r)
                    ((unsigned short*)T2s)[(wr * 32 + fm * 16 + cr4 + r) * 72 +
                                           wc * 32 + fn * 16 + cn] =
                        f2bf(accT[fm][fn][r]);
#pragma unroll
        for (int i = 0; i < 2; ++i) {
            int c = i * 256 + tid, v = c >> 3, kc = c & 7;
            gld_lds16(Vh + (size_t)v * DIN + j0 + kc * 8, Vs + c * 8);
        }
        __syncthreads();
#pragma unroll
        for (int kk = 0; kk < 64; kk += 32) {
            bf16x8 aF[2], bF[2];
#pragma unroll
            for (int f = 0; f < 2; ++f) {
                aF[f] = *(const bf16x8*)(T2s + (wr * 32 + f * 16 + cn) * 72 + kk +
                                         (lane >> 4) * 8);
                bF[f] = *(const bf16x8*)(Vs + (wc * 32 + f * 16 + cn) * 64 + kk +
                                         (lane >> 4) * 8);
            }
#pragma unroll
            for (int fm = 0; fm < 2; ++fm)
#pragma unroll
                for (int fn = 0; fn < 2; ++fn)
                    accM[fm][fn] = __builtin_amdgcn_mfma_f32_16x16x32_bf16(
                        aF[fm], bF[fn], accM[fm][fn], 0, 0, 0);
        }
        __syncthreads();
    }
    float* Mh = M32 + (size_t)(b * HDIM + h) * (DK * DV);
#pragma unroll
    for (int fm = 0; fm < 2; ++fm)
#pragma unroll
        for (int fn = 0; fn < 2; ++fn)
#pragma unroll
            for (int r = 0; r < 4; ++r)
                atomicAdd(&Mh[(wr * 32 + fm * 16 + cr4 + r) * 64 + wc * 32 +
                              fn * 16 + cn],
                          accM[fm][fn][r]);
}

// ---------------- K2: main (xtx atomic-G + Q' + piggybacked mid) ----------
__global__ __launch_bounds__(256) void k_main(char* __restrict__ ws) {
    __shared__ __align__(16) char smem[SMEM_MAIN];
    __shared__ int s_old;
    const bf16_t* xb  = (const bf16_t*)(ws + OFF_XB);
    const bf16_t* xT  = (const bf16_t*)(ws + OFF_XT);
    const bf16_t* WqT = (const bf16_t*)(ws + OFF_WQT);
    const bf16_t* WkT = (const bf16_t*)(ws + OFF_WKT);
    const bf16_t* WvT = (const bf16_t*)(ws + OFF_WVT);
    unsigned short* Qp = (unsigned short*)(ws + OFF_QP);
    float* G32 = (float*)(ws + OFF_G32);
    float* M32 = (float*)(ws + OFF_M32);
    unsigned* done = (unsigned*)ws;

    const int bid = blockIdx.x;
    const int tid = threadIdx.x;

    if (bid < NXTX) {
        // xtx: G[b] += xT-tile . xT-tile^T  (64x64 tile, K=1024 chunk)
        const int b = bid >> 8, r = bid & 255;
        const int chunk = r >> 6, t = r & 63;
        const int it = t >> 3, jt = t & 7;
        const bf16_t* Xb = xT + (size_t)b * DIN * LDIM + chunk * 1024;
        gemm_tn<64, 64, 64, 2>(smem, Xb, Xb, G32 + (size_t)b * DIN * DIN, 1024,
                               LDIM, LDIM, DIN, it * 64, jt * 64);
        __syncthreads();
        if (tid == 0) {
            unsigned old = __hip_atomic_fetch_add(done, 1u, __ATOMIC_RELAXED,
                                                  __HIP_MEMORY_SCOPE_SYSTEM);
            s_old = (int)old;
        }
        __syncthreads();
        int old = s_old;
        if (old >= NXTX - NMID) {
            if (tid == 0) {
                while (__hip_atomic_load(done, __ATOMIC_RELAXED,
                                         __HIP_MEMORY_SCOPE_SYSTEM) <
                       (unsigned)NXTX)
                    __builtin_amdgcn_s_sleep(8);
            }
            __syncthreads();
            mid_job(old - (NXTX - NMID), smem, WkT, WvT, G32, M32);
        }
    } else {
        // Q'[b][l][(h,dk)] = sum_i x[l][i] Wq[h][i][dk]   (128x128 tile)
        const int q = bid - NXTX;
        const int b = q >> 7, t = q & 127;
        const int lt = t >> 2, nt = t & 3;
        gemm_tn<128, 128, 64, 1>(smem, xb + (size_t)b * LDIM * DIN, WqT,
                                 Qp + (size_t)b * LDIM * (HDIM * DK), DIN, DIN,
                                 DIN, HDIM * DK, lt * 128, nt * 128);
    }
}

// ---------------- K3: out' ----------------
// per (lt, ot, b) 128x128 tile: loop h: P_h[dk][o] = M[b,h] . WoT[h][o][v];
// PT (transposed in LDS); out += Q'[l][(h,dk)] . PT[o][dk]
__global__ __launch_bounds__(256) void k_out(const char* __restrict__ ws,
                                             float* __restrict__ out) {
    __shared__ __align__(16) bf16_t Qs[128 * 64];
    __shared__ __align__(16) bf16_t Ws[128 * 64];
    __shared__ __align__(16) bf16_t Ms[64 * 72];
    __shared__ __align__(16) bf16_t PTs[128 * 72];
    const bf16_t* WoT = (const bf16_t*)(ws + OFF_WOT);
    const bf16_t* Qp  = (const bf16_t*)(ws + OFF_QP);
    const float* M32  = (const float*)(ws + OFF_M32);

    const int lt = blockIdx.x, nt = blockIdx.y, b = blockIdx.z;
    const int l0 = lt * 128, o0 = nt * 128;
    const int tid = threadIdx.x, lane = tid & 63;
    const int wr = (tid >> 7) & 1, wc = (tid >> 6) & 1;
    const int cr4 = (lane >> 4) * 4, cn = lane & 15;

    floatx4 acc[4][4] = {};

    for (int h = 0; h < HDIM; ++h) {
        // stage Ms: M32[b,h] fp32 -> bf16 [dk][v] (pad 72)
        {
            const float* Mh = M32 + (size_t)(b * HDIM + h) * (DK * DV);
            int dk = tid >> 2, v0 = (tid & 3) * 16;
            const float* s = Mh + dk * 64 + v0;
            unsigned short o[16];
#pragma unroll
            for (int q = 0; q < 4; ++q) {
                float4 v = *(const float4*)(s + q * 4);
                o[q * 4 + 0] = f2bf(v.x); o[q * 4 + 1] = f2bf(v.y);
                o[q * 4 + 2] = f2bf(v.z); o[q * 4 + 3] = f2bf(v.w);
            }
            unsigned short* d = (unsigned short*)Ms + dk * 72 + v0;
            *(uint4*)d = *(const uint4*)o;
            *(uint4*)(d + 8) = *(const uint4*)(o + 8);
        }
        // stage Ws: WoT[h][o0..o0+128)[v], Qs: Q'[l0..][h*64..]
#pragma unroll
        for (int i = 0; i < 4; ++i) {
            int c = i * 256 + tid, m = c >> 3, kc = c & 7;
            gld_lds16(WoT + ((size_t)h * DOUT + o0 + m) * DV + kc * 8,
                      Ws + c * 8);
            gld_lds16(Qp + (size_t)b * LDIM * 512 + (size_t)(l0 + m) * 512 +
                          h * 64 + kc * 8,
                      Qs + c * 8);
        }
        __syncthreads();

        // P-GEMM: P[dk][o] = sum_v Ms[dk][v] * Ws[o][v]  (wave-tile 32x64)
        floatx4 accP[2][4] = {};
#pragma unroll
        for (int kk = 0; kk < 64; kk += 32) {
            bf16x8 aF[2], bF[4];
#pragma unroll
            for (int f = 0; f < 2; ++f)
                aF[f] = *(const bf16x8*)(Ms + (wr * 32 + f * 16 + cn) * 72 + kk +
                                         (lane >> 4) * 8);
#pragma unroll
            for (int f = 0; f < 4; ++f)
                bF[f] = *(const bf16x8*)(Ws + (wc * 64 + f * 16 + cn) * 64 + kk +
                                         (lane >> 4) * 8);
#pragma unroll
            for (int fm = 0; fm < 2; ++fm)
#pragma unroll
                for (int fn = 0; fn < 4; ++fn)
                    accP[fm][fn] = __builtin_amdgcn_mfma_f32_16x16x32_bf16(
                        aF[fm], bF[fn], accP[fm][fn], 0, 0, 0);
        }
        // accP -> PTs transposed [o][dk] (pad 72)
#pragma unroll
        for (int fm = 0; fm < 2; ++fm)
#pragma unroll
            for (int fn = 0; fn < 4; ++fn)
#pragma unroll
                for (int r = 0; r < 4; ++r)
                    ((unsigned short*)PTs)[(wc * 64 + fn * 16 + cn) * 72 +
                                           wr * 32 + fm * 16 + cr4 + r] =
                        f2bf(accP[fm][fn][r]);
        __syncthreads();

        // out-GEMM: acc[l][o] += sum_dk Qs[l][dk] * PTs[o][dk]
#pragma unroll
        for (int kk = 0; kk < 64; kk += 32) {
            bf16x8 aF[4], bF[4];
#pragma unroll
            for (int f = 0; f < 4; ++f) {
                aF[f] = *(const bf16x8*)(Qs + (wr * 64 + f * 16 + cn) * 64 + kk +
                                         (lane >> 4) * 8);
                bF[f] = *(const bf16x8*)(PTs + (wc * 64 + f * 16 + cn) * 72 + kk +
                                         (lane >> 4) * 8);
            }
#pragma unroll
            for (int fm = 0; fm < 4; ++fm)
#pragma unroll
                for (int fn = 0; fn < 4; ++fn)
                    acc[fm][fn] = __builtin_amdgcn_mfma_f32_16x16x32_bf16(
                        aF[fm], bF[fn], acc[fm][fn], 0, 0, 0);
        }
        __syncthreads();
    }

    float* ob = out + (size_t)b * LDIM * DOUT;
#pragma unroll
    for (int fm = 0; fm < 4; ++fm)
#pragma unroll
        for (int fn = 0; fn < 4; ++fn)
#pragma unroll
            for (int r = 0; r < 4; ++r) {
                int m = l0 + wr * 64 + fm * 16 + cr4 + r;
                int n = o0 + wc * 64 + fn * 16 + cn;
                ob[(size_t)m * DOUT + n] = acc[fm][fn][r];
            }
}

extern "C" void kernel_launch(void* const* d_in, const int* in_sizes, int n_in,
                              void* d_out, int out_size, void* d_ws, size_t ws_size,
                              hipStream_t stream) {
    const float* x  = (const float*)d_in[0];
    const float* Wq = (const float*)d_in[1];
    const float* Wk = (const float*)d_in[2];
    const float* Wv = (const float*)d_in[3];
    const float* Wo = (const float*)d_in[4];

    k_prep<<<dim3(1416), 256, 0, stream>>>(x, Wq, Wk, Wv, Wo, (char*)d_ws);
    k_main<<<dim3(768), 256, 0, stream>>>((char*)d_ws);
    k_out<<<dim3(32, 4, BDIM), 256, 0, stream>>>((const char*)d_ws,
                                                 (float*)d_out);
}

// Round 6
// 151.331 us; speedup vs baseline: 4.8602x; 1.0809x over previous
//
#include <hip/hip_runtime.h>
#include <cstdint>

// out[b] = x[b] @ C[b],  C[b] = sum_h Wq[h] M[b,h] Wo[h],  M = Wk^T (x^T x) Wv
// R16: fix R15's mid TAIL (Occupancy 9.5%: 32 blocks re-reading 2MB fp32 G
// each at HBM latency while 224 CUs idle = ~35us of k_main's 67).
//   - mid: 32 -> 128 jobs (one (h,b,jt) each; 128KB G per job).
//   - M: bf16 per-jt partials, plain stores (k_out sums 8 across the launch
//     boundary -> no atomics, no zero-init).  [R13's proven scheme]
//   - xtx: 128x64 tiles (256 jobs), halves staging traffic.
// G stays fp32 atomicAdd (only proven within-kernel coherent path).
// 3 dispatches: prep | main (xtx+Q' + gated mid) | out.

#define BDIM 2
#define LDIM 4096
#define DIN 512
#define HDIM 8
#define DK 64
#define DV 64
#define DOUT 512
#define NXTX 256
#define NMID 128
#define SMEM_MAIN 34816

using bf16_t = __bf16;
typedef __bf16 bf16x8 __attribute__((ext_vector_type(8)));
typedef float floatx4 __attribute__((ext_vector_type(4)));

constexpr size_t OFF_XB  = 4096;
constexpr size_t OFF_XT  = OFF_XB  + (size_t)BDIM * LDIM * DIN * 2;
constexpr size_t OFF_WQT = OFF_XT  + (size_t)BDIM * LDIM * DIN * 2;
constexpr size_t OFF_WKT = OFF_WQT + (size_t)HDIM * DK * DIN * 2;
constexpr size_t OFF_WVT = OFF_WKT + (size_t)HDIM * DK * DIN * 2;
constexpr size_t OFF_WOT = OFF_WVT + (size_t)HDIM * DV * DIN * 2;
constexpr size_t OFF_QP  = OFF_WOT + (size_t)HDIM * DOUT * DV * 2;
constexpr size_t OFF_G32 = OFF_QP  + (size_t)BDIM * LDIM * DIN * 2;
constexpr size_t OFF_MP  = OFF_G32 + (size_t)BDIM * DIN * DIN * 4;

__device__ __forceinline__ unsigned short f2bf(float f) {
    unsigned int u = __builtin_bit_cast(unsigned int, f);
    u += 0x7FFFu + ((u >> 16) & 1u);
    return (unsigned short)(u >> 16);
}

__device__ __forceinline__ float bf2f(unsigned short u) {
    unsigned int v = ((unsigned int)u) << 16;
    return __builtin_bit_cast(float, v);
}

__device__ __forceinline__ void gld_lds16(const void* g, void* l) {
    __builtin_amdgcn_global_load_lds(
        (const __attribute__((address_space(1))) void*)g,
        (__attribute__((address_space(3))) void*)l, 16, 0, 0);
}

// ---------------- TN MFMA GEMM tile on caller-provided LDS ----------------
// C[m][n] = sum_k A[m][k] * B[n][k].  OUT_MODE: 1 = bf16 store, 2 = fp32
// atomicAdd.
template <int BM, int BN, int BK, int OUT_MODE>
__device__ __forceinline__ void gemm_tn(char* smem, const bf16_t* A,
                                        const bf16_t* B, void* Cp, int K,
                                        int lda, int ldb, int ldc, int tm,
                                        int tn) {
    constexpr int WM = BM / 2, WN = BN / 2;
    constexpr int FM = WM / 16, FN = WN / 16;
    constexpr int CPR = BK / 8;
    bf16_t* As = (bf16_t*)smem;
    bf16_t* Bs = As + BM * BK;
    const int tid = threadIdx.x;
    const int lane = tid & 63;
    const int wr = (tid >> 7) & 1;
    const int wc = (tid >> 6) & 1;

    A += (size_t)tm * lda;
    B += (size_t)tn * ldb;

    floatx4 acc[FM][FN] = {};

    for (int k0 = 0; k0 < K; k0 += BK) {
#pragma unroll
        for (int i = 0; i < (BM * CPR) / 256; ++i) {
            int c = i * 256 + tid;
            int m = c / CPR, kc = c % CPR;
            gld_lds16(A + (size_t)m * lda + k0 + kc * 8, As + c * 8);
        }
#pragma unroll
        for (int i = 0; i < (BN * CPR) / 256; ++i) {
            int c = i * 256 + tid;
            int m = c / CPR, kc = c % CPR;
            gld_lds16(B + (size_t)m * ldb + k0 + kc * 8, Bs + c * 8);
        }
        __syncthreads();

#pragma unroll
        for (int kk = 0; kk < BK; kk += 32) {
            bf16x8 aF[FM], bF[FN];
#pragma unroll
            for (int fm = 0; fm < FM; ++fm)
                aF[fm] = *(const bf16x8*)(As + (wr * WM + fm * 16 + (lane & 15)) * BK +
                                          kk + (lane >> 4) * 8);
#pragma unroll
            for (int fn = 0; fn < FN; ++fn)
                bF[fn] = *(const bf16x8*)(Bs + (wc * WN + fn * 16 + (lane & 15)) * BK +
                                          kk + (lane >> 4) * 8);
#pragma unroll
            for (int fm = 0; fm < FM; ++fm)
#pragma unroll
                for (int fn = 0; fn < FN; ++fn)
                    acc[fm][fn] = __builtin_amdgcn_mfma_f32_16x16x32_bf16(
                        aF[fm], bF[fn], acc[fm][fn], 0, 0, 0);
        }
        __syncthreads();
    }

    const int cr4 = (lane >> 4) * 4;
    const int cn = lane & 15;
#pragma unroll
    for (int fm = 0; fm < FM; ++fm)
#pragma unroll
        for (int fn = 0; fn < FN; ++fn)
#pragma unroll
            for (int r = 0; r < 4; ++r) {
                int m = tm + wr * WM + fm * 16 + cr4 + r;
                int n = tn + wc * WN + fn * 16 + cn;
                size_t idx = (size_t)m * ldc + n;
                if (OUT_MODE == 1)
                    ((unsigned short*)Cp)[idx] = f2bf(acc[fm][fn][r]);
                else
                    atomicAdd((float*)Cp + idx, acc[fm][fn][r]);
            }
}

// ---------------- K1: prep ----------------
// bids: [0,1024) x->xb16+xT | [1024,1280) W transposes | [1280,1344) zero G
//       | 1344 zero counter page
__global__ __launch_bounds__(256) void k_prep(
    const float* __restrict__ x, const float* __restrict__ Wq,
    const float* __restrict__ Wk, const float* __restrict__ Wv,
    const float* __restrict__ Wo, char* __restrict__ ws) {
    __shared__ unsigned short T[64][65];
    unsigned short* xb  = (unsigned short*)(ws + OFF_XB);
    unsigned short* xT  = (unsigned short*)(ws + OFF_XT);
    unsigned short* WqT = (unsigned short*)(ws + OFF_WQT);
    unsigned short* WkT = (unsigned short*)(ws + OFF_WKT);
    unsigned short* WvT = (unsigned short*)(ws + OFF_WVT);
    unsigned short* WoT = (unsigned short*)(ws + OFF_WOT);
    float* G32 = (float*)(ws + OFF_G32);

    const int tid = threadIdx.x;
    const int tr = tid >> 4, tc4 = (tid & 15) * 4;
    const int j = blockIdx.x;

    if (j < 1024) {  // x 64x64 tile -> xb16 (row-major) + xT (transposed)
        const int b = j >> 9, q = j & 511, lt = q >> 3, it = q & 7;
        const float* src = x + (size_t)b * LDIM * DIN + (size_t)lt * 64 * DIN +
                           it * 64;
        unsigned short* d0 = xb + (size_t)b * LDIM * DIN +
                             (size_t)lt * 64 * DIN + it * 64;
        unsigned short* d1 = xT + (size_t)b * DIN * LDIM +
                             (size_t)it * 64 * LDIM + lt * 64;
#pragma unroll
        for (int p = 0; p < 4; ++p) {
            int r = p * 16 + tr;
            float4 v = *(const float4*)(src + (size_t)r * DIN + tc4);
            ushort4 u = make_ushort4(f2bf(v.x), f2bf(v.y), f2bf(v.z), f2bf(v.w));
            *(ushort4*)(d0 + (size_t)r * DIN + tc4) = u;
            T[r][tc4 + 0] = u.x; T[r][tc4 + 1] = u.y;
            T[r][tc4 + 2] = u.z; T[r][tc4 + 3] = u.w;
        }
        __syncthreads();
#pragma unroll
        for (int p = 0; p < 4; ++p) {
            int c = p * 16 + tr;
            ushort4 u = make_ushort4(T[tc4 + 0][c], T[tc4 + 1][c], T[tc4 + 2][c],
                                     T[tc4 + 3][c]);
            *(ushort4*)(d1 + (size_t)c * LDIM + tc4) = u;
        }
        return;
    }
    if (j < 1280) {  // weight transposes -> bf16, k-contiguous layouts
        const int q = j - 1024;
        const int t = q & 7, h = (q >> 3) & 7, typ = q >> 6;
        const float* src;
        unsigned short* dst;
        int rows, cols, r0, c0;
        if (typ == 0) { src = Wq + (size_t)h * DIN * DK; dst = WqT + (size_t)h * DK * DIN;
                        rows = DIN; cols = DK; r0 = t * 64; c0 = 0; }
        else if (typ == 1) { src = Wk + (size_t)h * DIN * DK; dst = WkT + (size_t)h * DK * DIN;
                        rows = DIN; cols = DK; r0 = t * 64; c0 = 0; }
        else if (typ == 2) { src = Wv + (size_t)h * DIN * DV; dst = WvT + (size_t)h * DV * DIN;
                        rows = DIN; cols = DV; r0 = t * 64; c0 = 0; }
        else { src = Wo + (size_t)h * DV * DOUT; dst = WoT + (size_t)h * DOUT * DV;
                        rows = DV; cols = DOUT; r0 = 0; c0 = t * 64; }
#pragma unroll
        for (int p = 0; p < 4; ++p) {
            int r = p * 16 + tr;
            float4 v = *(const float4*)(src + (size_t)(r0 + r) * cols + c0 + tc4);
            T[r][tc4 + 0] = f2bf(v.x); T[r][tc4 + 1] = f2bf(v.y);
            T[r][tc4 + 2] = f2bf(v.z); T[r][tc4 + 3] = f2bf(v.w);
        }
        __syncthreads();
#pragma unroll
        for (int p = 0; p < 4; ++p) {
            int c = p * 16 + tr;
            ushort4 u = make_ushort4(T[tc4 + 0][c], T[tc4 + 1][c], T[tc4 + 2][c],
                                     T[tc4 + 3][c]);
            *(ushort4*)(dst + (size_t)(c0 + c) * rows + r0 + tc4) = u;
        }
        return;
    }
    if (j < 1344) {  // zero G32 (2x512x512 fp32 = 2 MB)
        float* g = G32 + (size_t)(j - 1280) * 8192 + tid * 32;
        float4 z = make_float4(0.f, 0.f, 0.f, 0.f);
#pragma unroll
        for (int q = 0; q < 8; ++q) *(float4*)(g + q * 4) = z;
        return;
    }
    {  // zero counter page (4 KB)
        ((uint4*)ws)[tid] = make_uint4(0u, 0u, 0u, 0u);
    }
}

// ---------------- mid job (runs inside K2, last NMID xtx finishers) -------
// job id -> (h, b, jt):  T2[dk][j] = sum_i WkT[h][dk][i] * G[b][j0+j][i]
// Mp[jt][b][h][dk][v] = sum_j T2[dk][j] * WvT[h][v][j0+j]   (bf16 partial,
// plain store; k_out sums the 8 jt partials across the launch boundary)
__device__ void mid_job(int id, char* smem, const bf16_t* WkT,
                        const bf16_t* WvT, const float* G32,
                        unsigned short* Mp) {
    const int tid = threadIdx.x, lane = tid & 63;
    const int wr = (tid >> 7) & 1, wc = (tid >> 6) & 1;
    const int cr4 = (lane >> 4) * 4, cn = lane & 15;
    const int h = id & 7, b = (id >> 3) & 1, jt = id >> 4;  // jt 0..7
    const int j0 = jt * 64;
    bf16_t* As  = (bf16_t*)smem;                 // 64x64
    bf16_t* Bs  = (bf16_t*)(smem + 8192);        // 64x64
    bf16_t* T2s = (bf16_t*)(smem + 16384);       // [64][72]
    bf16_t* Vs  = (bf16_t*)(smem + 25600);       // 64x64
    const bf16_t* Ah = WkT + (size_t)h * DK * DIN;
    const bf16_t* Vh = WvT + (size_t)h * DV * DIN;
    const float* Gb = G32 + (size_t)b * DIN * DIN;

    floatx4 accT[2][2] = {};
    for (int k0 = 0; k0 < DIN; k0 += 64) {
#pragma unroll
        for (int i = 0; i < 2; ++i) {
            int c = i * 256 + tid, m = c >> 3, kc = c & 7;
            gld_lds16(Ah + (size_t)m * DIN + k0 + kc * 8, As + c * 8);
        }
#pragma unroll
        for (int i = 0; i < 2; ++i) {
            int c = i * 256 + tid, n = c >> 3, kc = c & 7;
            const float* g = Gb + (size_t)(j0 + n) * DIN + k0 + kc * 8;
            float4 v0 = *(const float4*)g;
            float4 v1 = *(const float4*)(g + 4);
            unsigned short o[8] = {f2bf(v0.x), f2bf(v0.y), f2bf(v0.z),
                                   f2bf(v0.w), f2bf(v1.x), f2bf(v1.y),
                                   f2bf(v1.z), f2bf(v1.w)};
            *(uint4*)((unsigned short*)Bs + (size_t)c * 8) = *(const uint4*)o;
        }
        __syncthreads();
#pragma unroll
        for (int kk = 0; kk < 64; kk += 32) {
            bf16x8 aF[2], bF[2];
#pragma unroll
            for (int f = 0; f < 2; ++f) {
                aF[f] = *(const bf16x8*)(As + (wr * 32 + f * 16 + cn) * 64 + kk +
                                         (lane >> 4) * 8);
                bF[f] = *(const bf16x8*)(Bs + (wc * 32 + f * 16 + cn) * 64 + kk +
                                         (lane >> 4) * 8);
            }
#pragma unroll
            for (int fm = 0; fm < 2; ++fm)
#pragma unroll
                for (int fn = 0; fn < 2; ++fn)
                    accT[fm][fn] = __builtin_amdgcn_mfma_f32_16x16x32_bf16(
                        aF[fm], bF[fn], accT[fm][fn], 0, 0, 0);
        }
        __syncthreads();
    }
    // accT -> T2s [dk][j] (pad 72), stage Wv j-slice
#pragma unroll
    for (int fm = 0; fm < 2; ++fm)
#pragma unroll
        for (int fn = 0; fn < 2; ++fn)
#pragma unroll
            for (int r = 0; r < 4; ++r)
                ((unsigned short*)T2s)[(wr * 32 + fm * 16 + cr4 + r) * 72 +
                                       wc * 32 + fn * 16 + cn] =
                    f2bf(accT[fm][fn][r]);
#pragma unroll
    for (int i = 0; i < 2; ++i) {
        int c = i * 256 + tid, v = c >> 3, kc = c & 7;
        gld_lds16(Vh + (size_t)v * DIN + j0 + kc * 8, Vs + c * 8);
    }
    __syncthreads();

    floatx4 accM[2][2] = {};
#pragma unroll
    for (int kk = 0; kk < 64; kk += 32) {
        bf16x8 aF[2], bF[2];
#pragma unroll
        for (int f = 0; f < 2; ++f) {
            aF[f] = *(const bf16x8*)(T2s + (wr * 32 + f * 16 + cn) * 72 + kk +
                                     (lane >> 4) * 8);
            bF[f] = *(const bf16x8*)(Vs + (wc * 32 + f * 16 + cn) * 64 + kk +
                                     (lane >> 4) * 8);
        }
#pragma unroll
        for (int fm = 0; fm < 2; ++fm)
#pragma unroll
            for (int fn = 0; fn < 2; ++fn)
                accM[fm][fn] = __builtin_amdgcn_mfma_f32_16x16x32_bf16(
                    aF[fm], bF[fn], accM[fm][fn], 0, 0, 0);
    }
    unsigned short* MpD = Mp + ((size_t)((jt * BDIM + b) * HDIM + h)) * (DK * DV);
#pragma unroll
    for (int fm = 0; fm < 2; ++fm)
#pragma unroll
        for (int fn = 0; fn < 2; ++fn)
#pragma unroll
            for (int r = 0; r < 4; ++r)
                MpD[(wr * 32 + fm * 16 + cr4 + r) * 64 + wc * 32 + fn * 16 + cn] =
                    f2bf(accM[fm][fn][r]);
}

// ---------------- K2: main (xtx atomic-G + Q' + gated mid x128) -----------
__global__ __launch_bounds__(256) void k_main(char* __restrict__ ws) {
    __shared__ __align__(16) char smem[SMEM_MAIN];
    __shared__ int s_old;
    const bf16_t* xb  = (const bf16_t*)(ws + OFF_XB);
    const bf16_t* xT  = (const bf16_t*)(ws + OFF_XT);
    const bf16_t* WqT = (const bf16_t*)(ws + OFF_WQT);
    const bf16_t* WkT = (const bf16_t*)(ws + OFF_WKT);
    const bf16_t* WvT = (const bf16_t*)(ws + OFF_WVT);
    unsigned short* Qp = (unsigned short*)(ws + OFF_QP);
    float* G32 = (float*)(ws + OFF_G32);
    unsigned short* Mp = (unsigned short*)(ws + OFF_MP);
    unsigned* done = (unsigned*)ws;

    const int bid = blockIdx.x;
    const int tid = threadIdx.x;

    if (bid < NXTX) {
        // xtx: G[b] += xT-tile . xT-tile^T  (128x64 tile, K=1024 chunk)
        const int b = bid >> 7, r = bid & 127;
        const int ch = r >> 5, t = r & 31;
        const int i0 = (t >> 3) * 128, j0 = (t & 7) * 64;
        const bf16_t* Xb = xT + (size_t)b * DIN * LDIM + ch * 1024;
        gemm_tn<128, 64, 64, 2>(smem, Xb, Xb, G32 + (size_t)b * DIN * DIN, 1024,
                                LDIM, LDIM, DIN, i0, j0);
        __syncthreads();
        if (tid == 0) {
            unsigned old = __hip_atomic_fetch_add(done, 1u, __ATOMIC_RELAXED,
                                                  __HIP_MEMORY_SCOPE_AGENT);
            s_old = (int)old;
        }
        __syncthreads();
        int old = s_old;
        if (old >= NXTX - NMID) {
            if (tid == 0) {
                while (__hip_atomic_load(done, __ATOMIC_RELAXED,
                                         __HIP_MEMORY_SCOPE_AGENT) <
                       (unsigned)NXTX)
                    __builtin_amdgcn_s_sleep(8);
            }
            __syncthreads();
            mid_job(old - (NXTX - NMID), smem, WkT, WvT, G32, Mp);
        }
    } else {
        // Q'[b][l][(h,dk)] = sum_i x[l][i] Wq[h][i][dk]   (128x128 tile)
        const int q = bid - NXTX;
        const int b = q >> 7, t = q & 127;
        const int lt = t >> 2, nt = t & 3;
        gemm_tn<128, 128, 64, 1>(smem, xb + (size_t)b * LDIM * DIN, WqT,
                                 Qp + (size_t)b * LDIM * (HDIM * DK), DIN, DIN,
                                 DIN, HDIM * DK, lt * 128, nt * 128);
    }
}

// ---------------- K3: out' ----------------
// per (lt, ot, b) 128x128 tile: loop h: Ms = bf16(sum_jt Mp[jt][b][h]);
// P_h[dk][o] = Ms . WoT[h]; PT transposed in LDS; out += Q' . PT
__global__ __launch_bounds__(256) void k_out(const char* __restrict__ ws,
                                             float* __restrict__ out) {
    __shared__ __align__(16) bf16_t Qs[128 * 64];
    __shared__ __align__(16) bf16_t Ws[128 * 64];
    __shared__ __align__(16) bf16_t Ms[64 * 72];
    __shared__ __align__(16) bf16_t PTs[128 * 72];
    const bf16_t* WoT = (const bf16_t*)(ws + OFF_WOT);
    const bf16_t* Qp  = (const bf16_t*)(ws + OFF_QP);
    const unsigned short* Mp = (const unsigned short*)(ws + OFF_MP);

    const int lt = blockIdx.x, nt = blockIdx.y, b = blockIdx.z;
    const int l0 = lt * 128, o0 = nt * 128;
    const int tid = threadIdx.x, lane = tid & 63;
    const int wr = (tid >> 7) & 1, wc = (tid >> 6) & 1;
    const int cr4 = (lane >> 4) * 4, cn = lane & 15;

    floatx4 acc[4][4] = {};

    for (int h = 0; h < HDIM; ++h) {
        // stage Ms: sum 8 bf16 jt-partials -> bf16 [dk][v] (pad 72)
        {
            const int dk = tid >> 2, v0 = (tid & 3) * 16;
            float s[16] = {0.f, 0.f, 0.f, 0.f, 0.f, 0.f, 0.f, 0.f,
                           0.f, 0.f, 0.f, 0.f, 0.f, 0.f, 0.f, 0.f};
#pragma unroll
            for (int p = 0; p < 8; ++p) {
                const unsigned short* mp =
                    Mp + ((size_t)((p * BDIM + b) * HDIM + h)) * (DK * DV) +
                    dk * 64 + v0;
                uint4 u0 = *(const uint4*)mp;
                uint4 u1 = *(const uint4*)(mp + 8);
                const unsigned short* e0 = (const unsigned short*)&u0;
                const unsigned short* e1 = (const unsigned short*)&u1;
#pragma unroll
                for (int q = 0; q < 8; ++q) {
                    s[q] += bf2f(e0[q]);
                    s[8 + q] += bf2f(e1[q]);
                }
            }
            unsigned short o[16];
#pragma unroll
            for (int q = 0; q < 16; ++q) o[q] = f2bf(s[q]);
            unsigned short* d = (unsigned short*)Ms + dk * 72 + v0;
            *(uint4*)d = *(const uint4*)o;
            *(uint4*)(d + 8) = *(const uint4*)(o + 8);
        }
        // stage Ws: WoT[h][o0..o0+128)[v], Qs: Q'[l0..][h*64..]
#pragma unroll
        for (int i = 0; i < 4; ++i) {
            int c = i * 256 + tid, m = c >> 3, kc = c & 7;
            gld_lds16(WoT + ((size_t)h * DOUT + o0 + m) * DV + kc * 8,
                      Ws + c * 8);
            gld_lds16(Qp + (size_t)b * LDIM * 512 + (size_t)(l0 + m) * 512 +
                          h * 64 + kc * 8,
                      Qs + c * 8);
        }
        __syncthreads();

        // P-GEMM: P[dk][o] = sum_v Ms[dk][v] * Ws[o][v]  (wave-tile 32x64)
        floatx4 accP[2][4] = {};
#pragma unroll
        for (int kk = 0; kk < 64; kk += 32) {
            bf16x8 aF[2], bF[4];
#pragma unroll
            for (int f = 0; f < 2; ++f)
                aF[f] = *(const bf16x8*)(Ms + (wr * 32 + f * 16 + cn) * 72 + kk +
                                         (lane >> 4) * 8);
#pragma unroll
            for (int f = 0; f < 4; ++f)
                bF[f] = *(const bf16x8*)(Ws + (wc * 64 + f * 16 + cn) * 64 + kk +
                                         (lane >> 4) * 8);
#pragma unroll
            for (int fm = 0; fm < 2; ++fm)
#pragma unroll
                for (int fn = 0; fn < 4; ++fn)
                    accP[fm][fn] = __builtin_amdgcn_mfma_f32_16x16x32_bf16(
                        aF[fm], bF[fn], accP[fm][fn], 0, 0, 0);
        }
        // accP -> PTs transposed [o][dk] (pad 72)
#pragma unroll
        for (int fm = 0; fm < 2; ++fm)
#pragma unroll
            for (int fn = 0; fn < 4; ++fn)
#pragma unroll
                for (int r = 0; r < 4; ++r)
                    ((unsigned short*)PTs)[(wc * 64 + fn * 16 + cn) * 72 +
                                           wr * 32 + fm * 16 + cr4 + r] =
                        f2bf(accP[fm][fn][r]);
        __syncthreads();

        // out-GEMM: acc[l][o] += sum_dk Qs[l][dk] * PTs[o][dk]
#pragma unroll
        for (int kk = 0; kk < 64; kk += 32) {
            bf16x8 aF[4], bF[4];
#pragma unroll
            for (int f = 0; f < 4; ++f) {
                aF[f] = *(const bf16x8*)(Qs + (wr * 64 + f * 16 + cn) * 64 + kk +
                                         (lane >> 4) * 8);
                bF[f] = *(const bf16x8*)(PTs + (wc * 64 + f * 16 + cn) * 72 + kk +
                                         (lane >> 4) * 8);
            }
#pragma unroll
            for (int fm = 0; fm < 4; ++fm)
#pragma unroll
                for (int fn = 0; fn < 4; ++fn)
                    acc[fm][fn] = __builtin_amdgcn_mfma_f32_16x16x32_bf16(
                        aF[fm], bF[fn], acc[fm][fn], 0, 0, 0);
        }
        __syncthreads();
    }

    float* ob = out + (size_t)b * LDIM * DOUT;
#pragma unroll
    for (int fm = 0; fm < 4; ++fm)
#pragma unroll
        for (int fn = 0; fn < 4; ++fn)
#pragma unroll
            for (int r = 0; r < 4; ++r) {
                int m = l0 + wr * 64 + fm * 16 + cr4 + r;
                int n = o0 + wc * 64 + fn * 16 + cn;
                ob[(size_t)m * DOUT + n] = acc[fm][fn][r];
            }
}

extern "C" void kernel_launch(void* const* d_in, const int* in_sizes, int n_in,
                              void* d_out, int out_size, void* d_ws, size_t ws_size,
                              hipStream_t stream) {
    const float* x  = (const float*)d_in[0];
    const float* Wq = (const float*)d_in[1];
    const float* Wk = (const float*)d_in[2];
    const float* Wv = (const float*)d_in[3];
    const float* Wo = (const float*)d_in[4];

    k_prep<<<dim3(1345), 256, 0, stream>>>(x, Wq, Wk, Wv, Wo, (char*)d_ws);
    k_main<<<dim3(512), 256, 0, stream>>>((char*)d_ws);
    k_out<<<dim3(32, 4, BDIM), 256, 0, stream>>>((const char*)d_ws,
                                                 (float*)d_out);
}